// Round 1
// baseline (100.058 us; speedup 1.0000x reference)
//
#include <hip/hip_runtime.h>

// GaussianBasis: 2D gaussian splatting, N=10000 gaussians -> (3,256,256) fp32.
// Tile-based GATHER formulation (replaces atomic scatter):
//   Kernel A: per-gaussian precompute (center/conic/colors) + bin bbox into
//             per-16x16px-tile lists (footprint <= 13x15 px => <= 2x2 tiles).
//   Kernel B: one block per tile, one thread per pixel; stage gaussian params
//             into LDS (broadcast reads), accumulate 3 channels in registers,
//             fuse scale/shift on the direct store to out. No image atomics,
//             no acc memset, no finalize kernel.

#define IMG_H 256
#define IMG_W 256
#define TILE 16
#define TPX 16          // tiles per axis (256/16)
#define NTILES 256
#define CAP 4096        // max gaussians per tile list (avg ~100, worst ~300)

__global__ __launch_bounds__(256) void prep_bin_kernel(
    const float* __restrict__ xyz,      // (N,2)
    const float* __restrict__ chol,     // (N,3)
    const float* __restrict__ colors,   // (N,3)
    const float* __restrict__ opacity,  // (N,1)
    int N,
    int* __restrict__ counts,           // [NTILES]
    int* __restrict__ lists,            // [NTILES][CAP]
    float4* __restrict__ params)        // [N][3] : (cx,cy,a,b)(c,op,c0,c1)(c2,-,-,-)
{
    const int n = blockIdx.x * 256 + threadIdx.x;
    if (n >= N) return;

    const float mx = tanhf(xyz[2 * n + 0]);
    const float my = tanhf(xyz[2 * n + 1]);
    const float cx = 0.5f * IMG_W * (mx + 1.0f);
    const float cy = 0.5f * IMG_H * (my + 1.0f);

    const float L0 = chol[3 * n + 0] + 0.5f;
    const float L1 = chol[3 * n + 1];
    const float L2 = chol[3 * n + 2] + 0.5f;
    const float cov_xx = L0 * L0;
    const float cov_xy = L0 * L1;
    const float cov_yy = L1 * L1 + L2 * L2;
    const float det = cov_xx * cov_yy - cov_xy * cov_xy;  // = (L0*L2)^2 > 0

    const float conic_a = cov_yy / det;
    const float conic_b = -cov_xy / det;
    const float conic_c = cov_xx / det;
    const float op = opacity[n];

    params[3 * n + 0] = make_float4(cx, cy, conic_a, conic_b);
    params[3 * n + 1] = make_float4(conic_c, op, colors[3 * n + 0], colors[3 * n + 1]);
    params[3 * n + 2] = make_float4(colors[3 * n + 2], 0.0f, 0.0f, 0.0f);

    // alpha = op*exp(-sigma) >= 1/255  =>  sigma <= log(255*op) = smax
    const float smax = logf(255.0f * op);
    if (!(smax > 0.0f)) return;  // never visible

    const float rx = sqrtf(2.0f * smax * cov_xx) + 1.0f;
    const float ry = sqrtf(2.0f * smax * cov_yy) + 1.0f;
    const int x0 = max(0, (int)floorf(cx - rx));
    const int x1 = min(IMG_W - 1, (int)ceilf(cx + rx));
    const int y0 = max(0, (int)floorf(cy - ry));
    const int y1 = min(IMG_H - 1, (int)ceilf(cy + ry));
    if (x0 > x1 || y0 > y1) return;

    const int tx0 = x0 >> 4, tx1 = x1 >> 4;
    const int ty0 = y0 >> 4, ty1 = y1 >> 4;
    for (int ty = ty0; ty <= ty1; ++ty) {
        for (int tx = tx0; tx <= tx1; ++tx) {
            const int t = ty * TPX + tx;
            const int slot = atomicAdd(&counts[t], 1);
            if (slot < CAP) lists[t * CAP + slot] = n;
        }
    }
}

__global__ __launch_bounds__(256) void render_kernel(
    const int* __restrict__ counts,
    const int* __restrict__ lists,
    const float4* __restrict__ params,
    const float* __restrict__ scale,
    const float* __restrict__ shift,
    float* __restrict__ out)
{
    const int tile = blockIdx.x;
    const int tx = tile & (TPX - 1);
    const int ty = tile >> 4;
    const int lx = threadIdx.x & (TILE - 1);
    const int ly = threadIdx.x >> 4;
    const float px = (float)(tx * TILE + lx);
    const float py = (float)(ty * TILE + ly);

    __shared__ float4 sh[3 * 256];  // 12 KB

    const int cnt = min(counts[tile], CAP);
    const int* list = lists + tile * CAP;

    float accr = 0.0f, accg = 0.0f, accb = 0.0f;

    for (int base = 0; base < cnt; base += 256) {
        const int m = min(256, cnt - base);
        __syncthreads();
        if (threadIdx.x < m) {
            const int n = list[base + threadIdx.x];
            sh[3 * threadIdx.x + 0] = params[3 * n + 0];
            sh[3 * threadIdx.x + 1] = params[3 * n + 1];
            sh[3 * threadIdx.x + 2] = params[3 * n + 2];
        }
        __syncthreads();
        for (int j = 0; j < m; ++j) {
            const float4 p0 = sh[3 * j + 0];  // cx, cy, a, b  (LDS broadcast)
            const float4 p1 = sh[3 * j + 1];  // c, op, col0, col1
            const float c2v = sh[3 * j + 2].x;
            const float dx = p0.x - px;
            const float dy = p0.y - py;
            // exact reference expression for bit-similar threshold behavior
            const float sigma = 0.5f * (p0.z * dx * dx + p1.x * dy * dy) + p0.w * (dx * dy);
            float alpha = p1.y * expf(-sigma);
            if (sigma >= 0.0f && alpha >= (1.0f / 255.0f)) {
                alpha = fminf(alpha, 0.999f);
                accr = fmaf(alpha, p1.z, accr);
                accg = fmaf(alpha, p1.w, accg);
                accb = fmaf(alpha, c2v, accb);
            }
        }
    }

    const float s = scale[0];
    const float t = shift[0];
    const int pix = (ty * TILE + ly) * IMG_W + (tx * TILE + lx);
    out[0 * IMG_H * IMG_W + pix] = fmaf(accr, s, t);
    out[1 * IMG_H * IMG_W + pix] = fmaf(accg, s, t);
    out[2 * IMG_H * IMG_W + pix] = fmaf(accb, s, t);
}

extern "C" void kernel_launch(void* const* d_in, const int* in_sizes, int n_in,
                              void* d_out, int out_size, void* d_ws, size_t ws_size,
                              hipStream_t stream) {
    const float* xyz     = (const float*)d_in[0];
    const float* chol    = (const float*)d_in[1];
    const float* colors  = (const float*)d_in[2];
    const float* opacity = (const float*)d_in[3];
    const float* scale   = (const float*)d_in[4];
    const float* shift   = (const float*)d_in[5];
    float* out = (float*)d_out;

    const int N = in_sizes[3];  // opacity is (N,1)

    // ws layout: counts [256 ints] | lists [256*CAP ints] | params [N*3 float4]
    int* counts = (int*)d_ws;
    int* lists = counts + NTILES;
    float4* params = (float4*)(lists + NTILES * CAP);  // offset 4195328 B, 16B-aligned

    hipMemsetAsync(counts, 0, NTILES * sizeof(int), stream);
    prep_bin_kernel<<<(N + 255) / 256, 256, 0, stream>>>(
        xyz, chol, colors, opacity, N, counts, lists, params);
    render_kernel<<<NTILES, 256, 0, stream>>>(counts, lists, params, scale, shift, out);
}

// Round 2
// 76.413 us; speedup vs baseline: 1.3094x; 1.3094x over previous
//
#include <hip/hip_runtime.h>

// GaussianBasis: 2D gaussian splatting, N=10000 gaussians -> (3,256,256) fp32.
// Tile-based GATHER, v2:
//   - 8x8 pixel tiles (1024 tiles). Footprint <= 13 px => each gaussian touches
//     <= 3x3 tiles; total pairs ~57k, but pixel-evals halve vs 16x16 tiles.
//   - Binning counters padded to one per 64B cache line (kills the atomic
//     contention that sank v1: 29k atomics on 16 lines -> ~55 per line).
//   - Render: 1024 blocks x 256 thr (4 waves); wave s handles gaussians
//     j == s (mod 4) for all 64 pixels -> each list entry processed by exactly
//     one wave; 4-way partial RGB reduced through LDS at the end.
//   - __expf in the inner loop (tolerance >> approx error).

#define IMG_H 256
#define IMG_W 256
#define TILE 8
#define TPX 32          // tiles per axis (256/8)
#define NTILES 1024
#define CAP 512         // max gaussians per tile list (worst observed ~130)
#define CSTRIDE 16      // counter padding: 16 ints = 64 B line per counter

__global__ __launch_bounds__(64) void prep_bin_kernel(
    const float* __restrict__ xyz,      // (N,2)
    const float* __restrict__ chol,     // (N,3)
    const float* __restrict__ colors,   // (N,3)
    const float* __restrict__ opacity,  // (N,1)
    int N,
    int* __restrict__ counts,           // [NTILES*CSTRIDE]
    int* __restrict__ lists,            // [NTILES][CAP]
    float4* __restrict__ params)        // [N][3]: (cx,cy,a,b)(c,op,c0,c1)(c2,-,-,-)
{
    const int n = blockIdx.x * 64 + threadIdx.x;
    if (n >= N) return;

    const float mx = tanhf(xyz[2 * n + 0]);
    const float my = tanhf(xyz[2 * n + 1]);
    const float cx = 0.5f * IMG_W * (mx + 1.0f);
    const float cy = 0.5f * IMG_H * (my + 1.0f);

    const float L0 = chol[3 * n + 0] + 0.5f;
    const float L1 = chol[3 * n + 1];
    const float L2 = chol[3 * n + 2] + 0.5f;
    const float cov_xx = L0 * L0;
    const float cov_xy = L0 * L1;
    const float cov_yy = L1 * L1 + L2 * L2;
    const float det = cov_xx * cov_yy - cov_xy * cov_xy;  // = (L0*L2)^2 > 0

    const float conic_a = cov_yy / det;
    const float conic_b = -cov_xy / det;
    const float conic_c = cov_xx / det;
    const float op = opacity[n];

    params[3 * n + 0] = make_float4(cx, cy, conic_a, conic_b);
    params[3 * n + 1] = make_float4(conic_c, op, colors[3 * n + 0], colors[3 * n + 1]);
    params[3 * n + 2] = make_float4(colors[3 * n + 2], 0.0f, 0.0f, 0.0f);

    // alpha = op*exp(-sigma) >= 1/255  =>  sigma <= log(255*op) = smax
    const float smax = logf(255.0f * op);
    if (!(smax > 0.0f)) return;  // never visible

    const float rx = sqrtf(2.0f * smax * cov_xx) + 1.0f;
    const float ry = sqrtf(2.0f * smax * cov_yy) + 1.0f;
    const int x0 = max(0, (int)floorf(cx - rx));
    const int x1 = min(IMG_W - 1, (int)ceilf(cx + rx));
    const int y0 = max(0, (int)floorf(cy - ry));
    const int y1 = min(IMG_H - 1, (int)ceilf(cy + ry));
    if (x0 > x1 || y0 > y1) return;

    const int tx0 = x0 >> 3, tx1 = x1 >> 3;
    const int ty0 = y0 >> 3, ty1 = y1 >> 3;
    for (int ty = ty0; ty <= ty1; ++ty) {
        for (int tx = tx0; tx <= tx1; ++tx) {
            const int t = ty * TPX + tx;
            const int slot = atomicAdd(&counts[t * CSTRIDE], 1);
            if (slot < CAP) lists[t * CAP + slot] = n;
        }
    }
}

__global__ __launch_bounds__(256) void render_kernel(
    const int* __restrict__ counts,
    const int* __restrict__ lists,
    const float4* __restrict__ params,
    const float* __restrict__ scale,
    const float* __restrict__ shift,
    float* __restrict__ out)
{
    const int tile = blockIdx.x;
    const int tx = tile & (TPX - 1);
    const int ty = tile >> 5;
    const int wave = threadIdx.x >> 6;   // 0..3: gaussian slice
    const int p = threadIdx.x & 63;      // pixel within 8x8 tile
    const float px = (float)(tx * TILE + (p & (TILE - 1)));
    const float py = (float)(ty * TILE + (p >> 3));

    __shared__ float4 sh[3 * 256];       // 12 KB staged params
    __shared__ float red[3][256];        // 3 KB cross-wave reduction

    const int cnt = min(counts[tile * CSTRIDE], CAP);
    const int* list = lists + tile * CAP;

    float accr = 0.0f, accg = 0.0f, accb = 0.0f;

    for (int base = 0; base < cnt; base += 256) {
        const int m = min(256, cnt - base);
        __syncthreads();
        if (threadIdx.x < m) {
            const int n = list[base + threadIdx.x];
            sh[3 * threadIdx.x + 0] = params[3 * n + 0];
            sh[3 * threadIdx.x + 1] = params[3 * n + 1];
            sh[3 * threadIdx.x + 2] = params[3 * n + 2];
        }
        __syncthreads();
        // wave s handles j = s, s+4, s+8, ... : uniform j within a wave ->
        // LDS broadcast reads, and each list entry is touched by ONE wave.
        for (int j = wave; j < m; j += 4) {
            const float4 p0 = sh[3 * j + 0];  // cx, cy, a, b
            const float4 p1 = sh[3 * j + 1];  // c, op, col0, col1
            const float c2v = sh[3 * j + 2].x;
            const float dx = p0.x - px;
            const float dy = p0.y - py;
            const float sigma =
                0.5f * (p0.z * dx * dx + p1.x * dy * dy) + p0.w * (dx * dy);
            float alpha = p1.y * __expf(-sigma);
            if (sigma >= 0.0f && alpha >= (1.0f / 255.0f)) {
                alpha = fminf(alpha, 0.999f);
                accr = fmaf(alpha, p1.z, accr);
                accg = fmaf(alpha, p1.w, accg);
                accb = fmaf(alpha, c2v, accb);
            }
        }
    }

    red[0][threadIdx.x] = accr;
    red[1][threadIdx.x] = accg;
    red[2][threadIdx.x] = accb;
    __syncthreads();

    // threads 0..191: c = t>>6, pixel = t&63 ; sum the 4 wave-partials.
    if (threadIdx.x < 192) {
        const int c = threadIdx.x >> 6;
        const int q = threadIdx.x & 63;
        const float sum = red[c][q] + red[c][q + 64] + red[c][q + 128] + red[c][q + 192];
        const int pix = (ty * TILE + (q >> 3)) * IMG_W + tx * TILE + (q & (TILE - 1));
        out[c * IMG_H * IMG_W + pix] = fmaf(sum, scale[0], shift[0]);
    }
}

extern "C" void kernel_launch(void* const* d_in, const int* in_sizes, int n_in,
                              void* d_out, int out_size, void* d_ws, size_t ws_size,
                              hipStream_t stream) {
    const float* xyz     = (const float*)d_in[0];
    const float* chol    = (const float*)d_in[1];
    const float* colors  = (const float*)d_in[2];
    const float* opacity = (const float*)d_in[3];
    const float* scale   = (const float*)d_in[4];
    const float* shift   = (const float*)d_in[5];
    float* out = (float*)d_out;

    const int N = in_sizes[3];  // opacity is (N,1)

    // ws layout: counts [NTILES*CSTRIDE ints = 64 KB] | lists [NTILES*CAP ints = 2 MB]
    //            | params [N*3 float4 = 480 KB]
    int* counts = (int*)d_ws;
    int* lists = counts + NTILES * CSTRIDE;
    float4* params = (float4*)(lists + NTILES * CAP);  // 16B-aligned offset

    hipMemsetAsync(counts, 0, NTILES * CSTRIDE * sizeof(int), stream);
    prep_bin_kernel<<<(N + 63) / 64, 64, 0, stream>>>(
        xyz, chol, colors, opacity, N, counts, lists, params);
    render_kernel<<<NTILES, 256, 0, stream>>>(counts, lists, params, scale, shift, out);
}